// Round 1
// baseline (88150.061 us; speedup 1.0000x reference)
//
#include <hip/hip_runtime.h>
#include <hip/hip_cooperative_groups.h>
#include <math.h>

namespace cg = cooperative_groups;

#define TT 512
#define BB 64
#define II 512
#define HH 1024
#define OO 512

#define GRID 256
#define NTHR 512

__device__ __forceinline__ float sigmoidf_(float v) {
    return 1.0f / (1.0f + __expf(-v));
}

// Partial GEMM: for all 64 batch rows, cols [j0, j0+32), k in [k0, k0+klen):
//   target[b*tstride + j] += sum_k A[b][k] * W[k*wstride + j]
// A[b][k] = (k < asplit) ? a0[b*a0s + k] : a1[b*a1s + (k - asplit)]
// K-split across blocks; accumulate with fp32 atomicAdd (device scope,
// coherent across XCDs; grid.sync provides the release/acquire ordering).
__device__ void mm_partial(float (*A_lds)[68],
                           const float* __restrict__ a0, int a0s, int asplit,
                           const float* __restrict__ a1, int a1s,
                           const float* __restrict__ W, int wstride,
                           float* __restrict__ target, int tstride,
                           int j0, int k0, int klen)
{
    const int tid = threadIdx.x;
    const int jj = tid & 15;     // 16 groups of 2 cols
    const int bp = tid >> 4;     // 32 pairs of batch rows
    const int j  = j0 + jj * 2;
    const int b0 = bp * 2;

    float acc00 = 0.f, acc01 = 0.f, acc10 = 0.f, acc11 = 0.f;

    for (int kc = k0; kc < k0 + klen; kc += 64) {
        __syncthreads();
        // stage A chunk [64 b][64 k] into LDS (float4, coalesced; chunk never
        // straddles the x/h boundary since k0,kc are multiples of 64 and asplit=512)
        #pragma unroll
        for (int half = 0; half < 2; ++half) {
            int f  = tid + half * NTHR;      // 0..1023
            int b  = f >> 4;
            int c4 = (f & 15) << 2;
            int k  = kc + c4;
            const float* src = (k < asplit) ? (a0 + b * a0s + k)
                                            : (a1 + b * a1s + (k - asplit));
            float4 v = *reinterpret_cast<const float4*>(src);
            *reinterpret_cast<float4*>(&A_lds[b][c4]) = v;
        }
        __syncthreads();
        const float* wp = W + (size_t)kc * wstride + j;
        #pragma unroll 16
        for (int kk = 0; kk < 64; ++kk) {
            float av0 = A_lds[b0][kk];
            float av1 = A_lds[b0 + 1][kk];
            float2 w = *reinterpret_cast<const float2*>(wp);
            wp += wstride;
            acc00 = fmaf(av0, w.x, acc00);
            acc01 = fmaf(av0, w.y, acc01);
            acc10 = fmaf(av1, w.x, acc10);
            acc11 = fmaf(av1, w.y, acc11);
        }
    }
    atomicAdd(&target[(size_t)b0 * tstride + j],           acc00);
    atomicAdd(&target[(size_t)b0 * tstride + j + 1],       acc01);
    atomicAdd(&target[(size_t)(b0 + 1) * tstride + j],     acc10);
    atomicAdd(&target[(size_t)(b0 + 1) * tstride + j + 1], acc11);
}

// Single persistent cooperative kernel: entire T-loop inside, 4 grid syncs per
// step. Job->block mapping keeps each weight column-tile on a fixed XCD
// (bid & 7) so the ~2.6 MB/XCD weight slice stays L2-resident for all 512 steps.
__global__ __launch_bounds__(NTHR, 2) void gru_fused(
    const float* __restrict__ x,
    const float* __restrict__ Wz, const float* __restrict__ bz,
    const float* __restrict__ Wr, const float* __restrict__ br,
    const float* __restrict__ Wh, const float* __restrict__ bh,
    const float* __restrict__ Wo, const float* __restrict__ bo,
    float* __restrict__ out, float* __restrict__ ws)
{
    cg::grid_group grid = cg::this_grid();
    __shared__ float A_lds[64][68];

    float* h    = ws;                 // [64][1024] hidden state
    float* accz = ws + 1 * 65536;     // gate pre-activation accumulators
    float* accr = ws + 2 * 65536;
    float* accc = ws + 3 * 65536;
    float* zbuf = ws + 4 * 65536;     // sigmoid(z) latch
    float* hr   = ws + 5 * 65536;     // h * r

    const int bid  = blockIdx.x;
    const int tid  = threadIdx.x;
    const int gidx = bid * NTHR + tid;   // 0..131071
    const int xcd  = bid & 7;
    const int slot = bid >> 3;           // 0..31 within XCD

    // P0: zero h, pre-load biases into accumulators (ws is poisoned 0xAA)
    if (gidx < BB * HH) {
        int jm = gidx & (HH - 1);
        h[gidx]    = 0.0f;
        accz[gidx] = bz[jm];
        accr[gidx] = br[jm];
        accc[gidx] = bh[jm];
    }
    grid.sync();

    for (int t = 0; t < TT; ++t) {
        const float* xt = x + (size_t)t * BB * II;

        // PA: z,r pre-activation partials. 256 jobs = 2 gates x 32 col-tiles x 4 K-parts.
        {
            int gate = slot >> 4;                 // 0=z, 1=r
            int s2   = slot & 15;
            int tile = (s2 >> 2) * 8 + xcd;       // col-tile pinned to this XCD
            int kp   = s2 & 3;
            mm_partial(A_lds, xt, II, II, h, HH,
                       gate ? Wr : Wz, HH,
                       gate ? accr : accz, HH,
                       tile * 32, kp * 384, 384);
        }
        grid.sync();

        // PB: z = sig(accz); hr = h*sig(accr); re-arm accumulators; bias-init out[t]
        if (gidx < BB * HH) {
            int jm = gidx & (HH - 1);
            float zv = sigmoidf_(accz[gidx]);
            zbuf[gidx] = zv;
            accz[gidx] = bz[jm];
            float rv = sigmoidf_(accr[gidx]);
            hr[gidx]   = h[gidx] * rv;
            accr[gidx] = br[jm];
        } else if (gidx < BB * HH + BB * OO) {
            int i2 = gidx - BB * HH;
            out[(size_t)t * BB * OO + i2] = bo[i2 & (OO - 1)];
        }
        grid.sync();

        // PC: candidate partials (128 jobs) + out[t-1] partials (128 jobs).
        // h still holds h_{t-1} here, so out[t-1] = h_{t-1} @ Wo is safe.
        if (slot < 16) {
            int tile = (slot >> 2) * 8 + xcd;
            int kp   = slot & 3;
            mm_partial(A_lds, xt, II, II, hr, HH,
                       Wh, HH, accc, HH,
                       tile * 32, kp * 384, 384);
        } else if (t > 0) {
            int s2   = slot - 16;
            int tile = (s2 >> 3) * 8 + xcd;       // 16 tiles of 32 cols
            int kp   = s2 & 7;                    // 8 K-parts of 128
            mm_partial(A_lds, h, HH, 2048, h, HH,
                       Wo, OO, out + (size_t)(t - 1) * BB * OO, OO,
                       tile * 32, kp * 128, 128);
        }
        grid.sync();

        // PD: h = z*h + (1-z)*sig(accc); re-arm candidate accumulator
        if (gidx < BB * HH) {
            int jm = gidx & (HH - 1);
            float zv = zbuf[gidx];
            float cv = sigmoidf_(accc[gidx]);
            h[gidx]    = zv * h[gidx] + (1.0f - zv) * cv;
            accc[gidx] = bh[jm];
        }
        grid.sync();
    }

    // tail: out[T-1] = h_{T-1} @ Wo
    if (slot >= 16) {
        int s2   = slot - 16;
        int tile = (s2 >> 3) * 8 + xcd;
        int kp   = s2 & 7;
        mm_partial(A_lds, h, HH, 2048, h, HH,
                   Wo, OO, out + (size_t)(TT - 1) * BB * OO, OO,
                   tile * 32, kp * 128, 128);
    }
}

extern "C" void kernel_launch(void* const* d_in, const int* in_sizes, int n_in,
                              void* d_out, int out_size, void* d_ws, size_t ws_size,
                              hipStream_t stream)
{
    (void)in_sizes; (void)n_in; (void)out_size; (void)ws_size;
    const float* x  = (const float*)d_in[0];
    const float* Wz = (const float*)d_in[1];
    const float* bz = (const float*)d_in[2];
    const float* Wr = (const float*)d_in[3];
    const float* br = (const float*)d_in[4];
    const float* Wh = (const float*)d_in[5];
    const float* bh = (const float*)d_in[6];
    const float* Wo = (const float*)d_in[7];
    const float* bo = (const float*)d_in[8];
    float* out = (float*)d_out;
    float* ws  = (float*)d_ws;   // needs 6 * 64 * 1024 * 4 B = 1.5 MB

    void* args[] = { (void*)&x, (void*)&Wz, (void*)&bz, (void*)&Wr, (void*)&br,
                     (void*)&Wh, (void*)&bh, (void*)&Wo, (void*)&bo,
                     (void*)&out, (void*)&ws };
    hipLaunchCooperativeKernel(reinterpret_cast<void*>(gru_fused),
                               dim3(GRID), dim3(NTHR), args, 0, stream);
}

// Round 2
// 59308.911 us; speedup vs baseline: 1.4863x; 1.4863x over previous
//
#include <hip/hip_runtime.h>
#include <hip/hip_cooperative_groups.h>
#include <math.h>

namespace cg = cooperative_groups;

#define TT 512
#define BB 64
#define II 512
#define HH 1024
#define OO 512
#define KK 1536   // I + H

#define GRID 256
#define NTHR 512

// LDS weight slice strides (padded: 1540%32==4, 1028%32==4 -> conflict-free)
#define WGS 1540
#define WOS 1028

__device__ __forceinline__ float sigmoidf_(float v) {
    return 1.0f / (1.0f + __expf(-v));
}

// Persistent cooperative kernel. 256 blocks x 512 threads, 1 block/CU.
// Each block owns: 8 columns of ONE gate (z if bid<128 else r, full K=1536),
// 4 columns of the candidate (full K), 2 columns of Wo (out). Weight slices
// are staged to LDS once (sync-flush-immune). No atomics anywhere.
// 2 grid syncs per step:
//   Phase A: z,r pre-acts (full K) -> sigmoid -> zbuf/hr; out[t-1] = h@Wo.
//   Phase B: candidate (full K, A=[x|hr]) -> sigmoid -> h update (sole writer).
__global__ __launch_bounds__(NTHR, 2) void gru_fused(
    const float* __restrict__ x,
    const float* __restrict__ Wz, const float* __restrict__ bz,
    const float* __restrict__ Wr, const float* __restrict__ br,
    const float* __restrict__ Wh, const float* __restrict__ bh,
    const float* __restrict__ Wo, const float* __restrict__ bo,
    float* __restrict__ out, float* __restrict__ ws)
{
    cg::grid_group grid = cg::this_grid();

    __shared__ float wg[8 * WGS];   // gate weight slice, col-major, padded
    __shared__ float wh[4 * WGS];   // candidate slice
    __shared__ float wo[2 * WOS];   // out slice
    __shared__ float red[NTHR];     // reduction scratch

    float* h  = ws;                  // [64][1024]
    float* hr = ws + 1 * 65536;      // h * r
    float* zb = ws + 2 * 65536;      // sigmoid(z)

    const int bid = blockIdx.x;
    const int tid = threadIdx.x;

    // ---- stage weight slices to LDS (once) ----
    const bool is_r = (bid & 128) != 0;
    const float* Wg = is_r ? Wr : Wz;
    const int j0 = (bid & 127) * 8;          // gate col base
    for (int i = tid; i < KK * 8; i += NTHR) {
        int k = i >> 3, jj = i & 7;
        wg[jj * WGS + k] = Wg[(size_t)k * HH + j0 + jj];
    }
    const int j0h = bid * 4;                 // candidate col base
    for (int i = tid; i < KK * 4; i += NTHR) {
        int k = i >> 2, jj = i & 3;
        wh[jj * WGS + k] = Wh[(size_t)k * HH + j0h + jj];
    }
    const int j0o = bid * 2;                 // out col base
    for (int i = tid; i < HH * 2; i += NTHR) {
        int k = i >> 1, jj = i & 1;
        wo[jj * WOS + k] = Wo[(size_t)k * OO + j0o + jj];
    }

    // ---- init h = 0 (ws is poisoned 0xAA) ----
    {
        int g = bid * NTHR + tid;
        if (g < BB * HH) h[g] = 0.0f;
    }
    __syncthreads();

    // ---- per-thread fixed mappings ----
    // Phase A gate cell: 8 cols x 64 rows = 512 cells, 1/thread
    const int jj  = tid & 7;
    const int bA  = tid >> 3;
    const int jA  = j0 + jj;
    const float biasA = is_r ? br[jA] : bz[jA];
    // Phase A out partial: 2 cols x 64 rows x 4 K-quarters = 512, 1/thread
    const int ocell = tid >> 2;   // 0..127
    const int okq   = tid & 3;    // K quarter
    const int ojo   = ocell & 1;
    const int ob    = ocell >> 1; // batch row
    const int jout  = j0o + ojo;
    const float obias = bo[jout];
    // Phase B cand cell: 4 cols x 64 rows x 2 K-halves = 512, 1/thread
    const int bc  = tid & 255;
    const int bkh = tid >> 8;     // K half
    const int bj  = bc & 3;
    const int bb  = bc >> 2;      // batch row
    const int jB  = j0h + bj;
    const float biasB = bh[jB];

    grid.sync();

    for (int t = 0; t < TT; ++t) {
        const float* xt = x + (size_t)t * BB * II;

        // ================= Phase A =================
        {
            // gate cell: acc = bias + sum_k A[bA][k] * Wg[k][jA], K=1536
            const float* ax = xt + bA * II;
            const float* ah = h + bA * HH;
            const float* wrow = wg + jj * WGS;
            float s0 = 0.f, s1 = 0.f, s2 = 0.f, s3 = 0.f;
            #pragma unroll 8
            for (int q = 0; q < II / 4; ++q) {        // x part
                float4 a = *(const float4*)(ax + 4 * q);
                float4 w = *(const float4*)(wrow + 4 * q);
                s0 = fmaf(a.x, w.x, s0);
                s1 = fmaf(a.y, w.y, s1);
                s2 = fmaf(a.z, w.z, s2);
                s3 = fmaf(a.w, w.w, s3);
            }
            #pragma unroll 8
            for (int q = 0; q < HH / 4; ++q) {        // h part
                float4 a = *(const float4*)(ah + 4 * q);
                float4 w = *(const float4*)(wrow + II + 4 * q);
                s0 = fmaf(a.x, w.x, s0);
                s1 = fmaf(a.y, w.y, s1);
                s2 = fmaf(a.z, w.z, s2);
                s3 = fmaf(a.w, w.w, s3);
            }
            float val = sigmoidf_(biasA + ((s0 + s1) + (s2 + s3)));
            int idx = bA * HH + jA;
            if (is_r) hr[idx] = h[idx] * val;
            else      zb[idx] = val;
        }
        {
            // out[t-1] partial: K quarter of h_{t-1} @ Wo (h stable in A)
            const float* ohp = h + ob * HH + okq * 256;
            const float* owp = wo + ojo * WOS + okq * 256;
            float s0 = 0.f, s1 = 0.f, s2 = 0.f, s3 = 0.f;
            #pragma unroll 8
            for (int q = 0; q < 64; ++q) {
                float4 a = *(const float4*)(ohp + 4 * q);
                float4 w = *(const float4*)(owp + 4 * q);
                s0 = fmaf(a.x, w.x, s0);
                s1 = fmaf(a.y, w.y, s1);
                s2 = fmaf(a.z, w.z, s2);
                s3 = fmaf(a.w, w.w, s3);
            }
            red[tid] = (s0 + s1) + (s2 + s3);
            __syncthreads();
            if (okq == 0 && t > 0) {
                float tot = obias + ((red[tid] + red[tid + 1]) +
                                     (red[tid + 2] + red[tid + 3]));
                out[(size_t)(t - 1) * BB * OO + ob * OO + jout] = tot;
            }
        }
        grid.sync();

        // ================= Phase B =================
        {
            // candidate cell, K half: A = [x_t | hr]
            const float* wrow = wh + bj * WGS;
            float s0 = 0.f, s1 = 0.f, s2 = 0.f, s3 = 0.f;
            if (bkh == 0) {
                const float* ax = xt + bb * II;
                #pragma unroll 8
                for (int q = 0; q < II / 4; ++q) {    // k 0..512 (x)
                    float4 a = *(const float4*)(ax + 4 * q);
                    float4 w = *(const float4*)(wrow + 4 * q);
                    s0 = fmaf(a.x, w.x, s0);
                    s1 = fmaf(a.y, w.y, s1);
                    s2 = fmaf(a.z, w.z, s2);
                    s3 = fmaf(a.w, w.w, s3);
                }
                const float* ar = hr + bb * HH;
                #pragma unroll 8
                for (int q = 0; q < 64; ++q) {        // k 512..768 (hr 0..256)
                    float4 a = *(const float4*)(ar + 4 * q);
                    float4 w = *(const float4*)(wrow + II + 4 * q);
                    s0 = fmaf(a.x, w.x, s0);
                    s1 = fmaf(a.y, w.y, s1);
                    s2 = fmaf(a.z, w.z, s2);
                    s3 = fmaf(a.w, w.w, s3);
                }
            } else {
                const float* ar = hr + bb * HH + 256;
                #pragma unroll 8
                for (int q = 0; q < 192; ++q) {       // k 768..1536 (hr 256..1024)
                    float4 a = *(const float4*)(ar + 4 * q);
                    float4 w = *(const float4*)(wrow + 768 + 4 * q);
                    s0 = fmaf(a.x, w.x, s0);
                    s1 = fmaf(a.y, w.y, s1);
                    s2 = fmaf(a.z, w.z, s2);
                    s3 = fmaf(a.w, w.w, s3);
                }
            }
            float part = (s0 + s1) + (s2 + s3);
            red[tid] = part;
            __syncthreads();
            if (bkh == 0) {
                float pre = biasB + part + red[tid + 256];
                float cv  = sigmoidf_(pre);
                int idx = bb * HH + jB;
                float z = zb[idx];
                h[idx] = z * h[idx] + (1.0f - z) * cv;  // sole writer of this col
            }
        }
        grid.sync();
    }

    // ---- tail: out[T-1] = h_{T-1} @ Wo ----
    {
        const float* ohp = h + ob * HH + okq * 256;
        const float* owp = wo + ojo * WOS + okq * 256;
        float s0 = 0.f, s1 = 0.f, s2 = 0.f, s3 = 0.f;
        #pragma unroll 8
        for (int q = 0; q < 64; ++q) {
            float4 a = *(const float4*)(ohp + 4 * q);
            float4 w = *(const float4*)(owp + 4 * q);
            s0 = fmaf(a.x, w.x, s0);
            s1 = fmaf(a.y, w.y, s1);
            s2 = fmaf(a.z, w.z, s2);
            s3 = fmaf(a.w, w.w, s3);
        }
        red[tid] = (s0 + s1) + (s2 + s3);
        __syncthreads();
        if (okq == 0) {
            float tot = obias + ((red[tid] + red[tid + 1]) +
                                 (red[tid + 2] + red[tid + 3]));
            out[(size_t)(TT - 1) * BB * OO + ob * OO + jout] = tot;
        }
    }
}

extern "C" void kernel_launch(void* const* d_in, const int* in_sizes, int n_in,
                              void* d_out, int out_size, void* d_ws, size_t ws_size,
                              hipStream_t stream)
{
    (void)in_sizes; (void)n_in; (void)out_size; (void)ws_size;
    const float* x  = (const float*)d_in[0];
    const float* Wz = (const float*)d_in[1];
    const float* bz = (const float*)d_in[2];
    const float* Wr = (const float*)d_in[3];
    const float* br = (const float*)d_in[4];
    const float* Wh = (const float*)d_in[5];
    const float* bh = (const float*)d_in[6];
    const float* Wo = (const float*)d_in[7];
    const float* bo = (const float*)d_in[8];
    float* out = (float*)d_out;
    float* ws  = (float*)d_ws;   // needs 3 * 64 * 1024 * 4 B = 768 KB

    void* args[] = { (void*)&x, (void*)&Wz, (void*)&bz, (void*)&Wr, (void*)&br,
                     (void*)&Wh, (void*)&bh, (void*)&Wo, (void*)&bo,
                     (void*)&out, (void*)&ws };
    hipLaunchCooperativeKernel(reinterpret_cast<void*>(gru_fused),
                               dim3(GRID), dim3(NTHR), args, 0, stream);
}

// Round 4
// 52058.801 us; speedup vs baseline: 1.6933x; 1.1393x over previous
//
#include <hip/hip_runtime.h>
#include <math.h>

#define TT 512
#define BB 64
#define II 512
#define HH 1024
#define OO 512
#define KK 1536   // I + H

#define GRID 256
#define NTHR 512

// LDS weight strides. WGS: 1540 % 32 == 4 -> gate/cand rows conflict-free.
// Wo stored with a 4-float skew per 256-float K-quarter: quarter q starts at
// q*260 -> banks 0/4/8/12 (+16 for col 1): conflict-free across okq threads.
#define WGS 1540
#define WOS2 1040   // 4 * 260

__device__ __forceinline__ float sigmoidf_(float v) {
    return 1.0f / (1.0f + __expf(-v));
}

// ---- coherent (LLC / cross-XCD) scalar access for mutable shared state ----
__device__ __forceinline__ float ld_sys(const float* p) {
    float v;
    asm volatile("global_load_dword %0, %1, off sc0 sc1\n\ts_waitcnt vmcnt(0)"
                 : "=v"(v) : "v"(p) : "memory");
    return v;
}
__device__ __forceinline__ void st_sys(float* p, float v) {
    asm volatile("global_store_dword %0, %1, off sc0 sc1"
                 :: "v"(p), "v"(v) : "memory");
}

#define FMA4(av, wv) do { s0 = fmaf((av).x, (wv).x, s0); s1 = fmaf((av).y, (wv).y, s1); \
                          s2 = fmaf((av).z, (wv).z, s2); s3 = fmaf((av).w, (wv).w, s3); } while (0)

// 64 floats of A from global via 16 coherent dwordx4 (16 in flight, one wait),
// dotted against 64 contiguous LDS floats. p, w must be 16B-aligned.
// Outputs are EARLYCLOBBER ("=&v"): they are written while the address %16 is
// still live for later loads in the batch — without &, the allocator may
// overlap them with the address pair (R3 crash: corrupted base -> mem fault).
__device__ __forceinline__ void dot16_sys(const float* p, const float* w,
                                          float& s0, float& s1, float& s2, float& s3)
{
    float4 a0,a1,a2,a3,a4,a5,a6,a7,a8,a9,a10,a11,a12,a13,a14,a15;
    asm volatile(
        "global_load_dwordx4 %0, %16, off sc0 sc1\n\t"
        "global_load_dwordx4 %1, %16, off offset:16 sc0 sc1\n\t"
        "global_load_dwordx4 %2, %16, off offset:32 sc0 sc1\n\t"
        "global_load_dwordx4 %3, %16, off offset:48 sc0 sc1\n\t"
        "global_load_dwordx4 %4, %16, off offset:64 sc0 sc1\n\t"
        "global_load_dwordx4 %5, %16, off offset:80 sc0 sc1\n\t"
        "global_load_dwordx4 %6, %16, off offset:96 sc0 sc1\n\t"
        "global_load_dwordx4 %7, %16, off offset:112 sc0 sc1\n\t"
        "global_load_dwordx4 %8, %16, off offset:128 sc0 sc1\n\t"
        "global_load_dwordx4 %9, %16, off offset:144 sc0 sc1\n\t"
        "global_load_dwordx4 %10, %16, off offset:160 sc0 sc1\n\t"
        "global_load_dwordx4 %11, %16, off offset:176 sc0 sc1\n\t"
        "global_load_dwordx4 %12, %16, off offset:192 sc0 sc1\n\t"
        "global_load_dwordx4 %13, %16, off offset:208 sc0 sc1\n\t"
        "global_load_dwordx4 %14, %16, off offset:224 sc0 sc1\n\t"
        "global_load_dwordx4 %15, %16, off offset:240 sc0 sc1\n\t"
        "s_waitcnt vmcnt(0)"
        : "=&v"(a0),"=&v"(a1),"=&v"(a2),"=&v"(a3),
          "=&v"(a4),"=&v"(a5),"=&v"(a6),"=&v"(a7),
          "=&v"(a8),"=&v"(a9),"=&v"(a10),"=&v"(a11),
          "=&v"(a12),"=&v"(a13),"=&v"(a14),"=&v"(a15)
        : "v"(p)
        : "memory");
    const float4* wv = (const float4*)w;
    FMA4(a0,  wv[0]);  FMA4(a1,  wv[1]);  FMA4(a2,  wv[2]);  FMA4(a3,  wv[3]);
    FMA4(a4,  wv[4]);  FMA4(a5,  wv[5]);  FMA4(a6,  wv[6]);  FMA4(a7,  wv[7]);
    FMA4(a8,  wv[8]);  FMA4(a9,  wv[9]);  FMA4(a10, wv[10]); FMA4(a11, wv[11]);
    FMA4(a12, wv[12]); FMA4(a13, wv[13]); FMA4(a14, wv[14]); FMA4(a15, wv[15]);
}

// Flush-free grid barrier: drain this wave's (coherent) stores, block-sync,
// leader bumps a monotone agent-scope counter and sleep-spins to the target.
// No L2 writeback/invalidate -> read-only data stays cached all run.
__device__ __forceinline__ void gbar(unsigned* ctr, unsigned target, int tid)
{
    asm volatile("s_waitcnt vmcnt(0)" ::: "memory");
    __syncthreads();
    if (tid == 0) {
        __hip_atomic_fetch_add(ctr, 1u, __ATOMIC_RELAXED, __HIP_MEMORY_SCOPE_AGENT);
        while (__hip_atomic_load(ctr, __ATOMIC_RELAXED, __HIP_MEMORY_SCOPE_AGENT) < target)
            __builtin_amdgcn_s_sleep(2);
    }
    __syncthreads();
}

__global__ void zero_ctr(unsigned* c) { *c = 0u; }

// Persistent kernel, 256 blocks x 512 threads, 1 block/CU (LDS ~84 KB).
// Per block: 8 cols of one gate (z: bid<128, r: bid>=128), 4 candidate cols,
// 2 out cols — weight slices in LDS. 2 custom barriers per step.
__global__ __launch_bounds__(NTHR, 2) void gru_fused(
    const float* __restrict__ x,
    const float* __restrict__ Wz, const float* __restrict__ bz,
    const float* __restrict__ Wr, const float* __restrict__ br,
    const float* __restrict__ Wh, const float* __restrict__ bh,
    const float* __restrict__ Wo, const float* __restrict__ bo,
    float* __restrict__ out, float* __restrict__ ws)
{
    __shared__ float wg[8 * WGS];
    __shared__ float wh[4 * WGS];
    __shared__ float wo[2 * WOS2];
    __shared__ float red[NTHR];

    float* h  = ws;                  // [64][1024]  (coherent access)
    float* hr = ws + 1 * 65536;      // h * r       (coherent)
    float* zb = ws + 2 * 65536;      // sigmoid(z)  (coherent)
    unsigned* ctr = (unsigned*)(ws + 3 * 65536);

    const int bid = blockIdx.x;
    const int tid = threadIdx.x;

    // ---- stage weight slices to LDS (once; normal cached loads) ----
    const bool is_r = (bid & 128) != 0;
    const float* Wg = is_r ? Wr : Wz;
    const int j0 = (bid & 127) * 8;
    for (int i = tid; i < KK * 8; i += NTHR) {
        int k = i >> 3, jj = i & 7;
        wg[jj * WGS + k] = Wg[(size_t)k * HH + j0 + jj];
    }
    const int j0h = bid * 4;
    for (int i = tid; i < KK * 4; i += NTHR) {
        int k = i >> 2, jj = i & 3;
        wh[jj * WGS + k] = Wh[(size_t)k * HH + j0h + jj];
    }
    const int j0o = bid * 2;
    for (int i = tid; i < HH * 2; i += NTHR) {   // skewed K-quarter layout
        int k = i >> 1, jj = i & 1;
        wo[jj * WOS2 + (k >> 8) * 260 + (k & 255)] = Wo[(size_t)k * OO + j0o + jj];
    }

    // ---- init h = 0 (coherent stores; ws is poisoned 0xAA) ----
    {
        int g = bid * NTHR + tid;
        if (g < BB * HH) st_sys(&h[g], 0.0f);
    }

    // ---- per-thread fixed mappings (same as R2) ----
    const int jj  = tid & 7;
    const int bA  = tid >> 3;
    const int jA  = j0 + jj;
    const float biasA = is_r ? br[jA] : bz[jA];

    const int ocell = tid >> 2;
    const int okq   = tid & 3;
    const int ojo   = ocell & 1;
    const int ob    = ocell >> 1;
    const int jout  = j0o + ojo;
    const float obias = bo[jout];

    const int bc  = tid & 255;
    const int bkh = tid >> 8;
    const int bj  = bc & 3;
    const int bb  = bc >> 2;
    const int jB  = j0h + bj;
    const float biasB = bh[jB];

    unsigned tgt = GRID;
    gbar(ctr, tgt, tid);

    for (int t = 0; t < TT; ++t) {
        const float* xt = x + (size_t)t * BB * II;

        // ================= Phase A =================
        {
            // gate cell: K=1536. x part cached, h part coherent batches.
            const float* ax   = xt + bA * II;
            const float* ah   = h + bA * HH;
            const float* wrow = wg + jj * WGS;
            float s0 = 0.f, s1 = 0.f, s2 = 0.f, s3 = 0.f;
            #pragma unroll 8
            for (int q = 0; q < II / 4; ++q) {
                float4 a = *(const float4*)(ax + 4 * q);
                float4 w = *(const float4*)(wrow + 4 * q);
                FMA4(a, w);
            }
            for (int b = 0; b < 16; ++b)
                dot16_sys(ah + b * 64, wrow + II + b * 64, s0, s1, s2, s3);
            float val = sigmoidf_(biasA + ((s0 + s1) + (s2 + s3)));
            int idx = bA * HH + jA;
            if (is_r) st_sys(&hr[idx], ld_sys(&h[idx]) * val);
            else      st_sys(&zb[idx], val);
        }
        {
            // out[t-1] K-quarter partial: h coherent, Wo from skewed LDS
            const float* ohp = h + ob * HH + okq * 256;
            const float* owp = wo + ojo * WOS2 + okq * 260;
            float s0 = 0.f, s1 = 0.f, s2 = 0.f, s3 = 0.f;
            for (int b = 0; b < 4; ++b)
                dot16_sys(ohp + b * 64, owp + b * 64, s0, s1, s2, s3);
            red[tid] = (s0 + s1) + (s2 + s3);
            __syncthreads();
            if (okq == 0 && t > 0) {
                float tot = obias + ((red[tid] + red[tid + 1]) +
                                     (red[tid + 2] + red[tid + 3]));
                out[(size_t)(t - 1) * BB * OO + ob * OO + jout] = tot;
            }
        }
        tgt += GRID; gbar(ctr, tgt, tid);

        // ================= Phase B =================
        {
            const float* wrow = wh + bj * WGS;
            float s0 = 0.f, s1 = 0.f, s2 = 0.f, s3 = 0.f;
            if (bkh == 0) {
                const float* ax = xt + bb * II;
                #pragma unroll 8
                for (int q = 0; q < II / 4; ++q) {
                    float4 a = *(const float4*)(ax + 4 * q);
                    float4 w = *(const float4*)(wrow + 4 * q);
                    FMA4(a, w);
                }
                const float* ar = hr + bb * HH;
                for (int b = 0; b < 4; ++b)                  // k 512..768
                    dot16_sys(ar + b * 64, wrow + II + b * 64, s0, s1, s2, s3);
            } else {
                const float* ar = hr + bb * HH + 256;
                for (int b = 0; b < 12; ++b)                 // k 768..1536
                    dot16_sys(ar + b * 64, wrow + 768 + b * 64, s0, s1, s2, s3);
            }
            float part = (s0 + s1) + (s2 + s3);
            red[tid] = part;
            __syncthreads();
            if (bkh == 0) {
                float pre = biasB + part + red[tid + 256];
                float cv  = sigmoidf_(pre);
                int idx = bb * HH + jB;
                float z    = ld_sys(&zb[idx]);
                float hold = ld_sys(&h[idx]);
                st_sys(&h[idx], z * hold + (1.0f - z) * cv);
            }
        }
        tgt += GRID; gbar(ctr, tgt, tid);
    }

    // ---- tail: out[T-1] = h_{T-1} @ Wo ----
    {
        const float* ohp = h + ob * HH + okq * 256;
        const float* owp = wo + ojo * WOS2 + okq * 260;
        float s0 = 0.f, s1 = 0.f, s2 = 0.f, s3 = 0.f;
        for (int b = 0; b < 4; ++b)
            dot16_sys(ohp + b * 64, owp + b * 64, s0, s1, s2, s3);
        red[tid] = (s0 + s1) + (s2 + s3);
        __syncthreads();
        if (okq == 0) {
            float tot = obias + ((red[tid] + red[tid + 1]) +
                                 (red[tid + 2] + red[tid + 3]));
            out[(size_t)(TT - 1) * BB * OO + ob * OO + jout] = tot;
        }
    }
}

extern "C" void kernel_launch(void* const* d_in, const int* in_sizes, int n_in,
                              void* d_out, int out_size, void* d_ws, size_t ws_size,
                              hipStream_t stream)
{
    (void)in_sizes; (void)n_in; (void)out_size; (void)ws_size;
    const float* x  = (const float*)d_in[0];
    const float* Wz = (const float*)d_in[1];
    const float* bz = (const float*)d_in[2];
    const float* Wr = (const float*)d_in[3];
    const float* br = (const float*)d_in[4];
    const float* Wh = (const float*)d_in[5];
    const float* bh = (const float*)d_in[6];
    const float* Wo = (const float*)d_in[7];
    const float* bo = (const float*)d_in[8];
    float* out = (float*)d_out;
    float* ws  = (float*)d_ws;   // 3*65536 floats state + barrier counter

    zero_ctr<<<1, 1, 0, stream>>>((unsigned*)(ws + 3 * 65536));

    void* args[] = { (void*)&x, (void*)&Wz, (void*)&bz, (void*)&Wr, (void*)&br,
                     (void*)&Wh, (void*)&bh, (void*)&Wo, (void*)&bo,
                     (void*)&out, (void*)&ws };
    hipLaunchCooperativeKernel(reinterpret_cast<void*>(gru_fused),
                               dim3(GRID), dim3(NTHR), args, 0, stream);
}